// Round 10
// baseline (258.007 us; speedup 1.0000x reference)
//
#include <hip/hip_runtime.h>

typedef __bf16 bf16x8 __attribute__((ext_vector_type(8)));
typedef float f32x4 __attribute__((ext_vector_type(4)));
typedef unsigned short us8 __attribute__((ext_vector_type(8)));

#define GAS __attribute__((address_space(1)))
#define LAS __attribute__((address_space(3)))

__device__ __forceinline__ unsigned short f32_to_bf16(float f) {
    unsigned int u = __float_as_uint(f);
    u += 0x7FFFu + ((u >> 16) & 1u);   // round-to-nearest-even
    return (unsigned short)(u >> 16);
}

__device__ __forceinline__ float bf16_to_f32(unsigned short h) {
    return __uint_as_float((unsigned int)h << 16);
}

__device__ __forceinline__ void load16(const unsigned short* g, unsigned short* l) {
    // async global->LDS, 16B per lane; LDS dest is wave-uniform base + lane*16
    __builtin_amdgcn_global_load_lds((GAS unsigned int*)g, (LAS unsigned int*)l, 16, 0, 0);
}

// ---------------------------------------------------------------------------
// prep (1024 threads): blocks [0,1536) convert x fp32->bf16 float4-wide;
// blocks [1536,3264) transpose the three 768x768 weights to bf16.
// ---------------------------------------------------------------------------
__global__ __launch_bounds__(1024) void prep(
    const float* __restrict__ x, unsigned short* __restrict__ Xbf,
    const float* __restrict__ W0, const float* __restrict__ W1, const float* __restrict__ W2,
    unsigned short* __restrict__ T0, unsigned short* __restrict__ T1, unsigned short* __restrict__ T2)
{
    __shared__ float tile[32][33];
    const int id = blockIdx.x;
    const int t = threadIdx.x;
    if (id < 1536) {
        int i = id * 1024 + t;
        float4 v = ((const float4*)x)[i];
        ushort4 o;
        o.x = f32_to_bf16(v.x); o.y = f32_to_bf16(v.y);
        o.z = f32_to_bf16(v.z); o.w = f32_to_bf16(v.w);
        ((ushort4*)Xbf)[i] = o;
    } else {
        const int tid = id - 1536;               // 0..1727
        const int z = tid / 576, rem = tid % 576;
        const int by = rem / 24, bx = rem % 24;
        const float* W = (z == 0) ? W0 : (z == 1) ? W1 : W2;
        unsigned short* T = (z == 0) ? T0 : (z == 1) ? T1 : T2;
        const int r0 = by * 32, c0 = bx * 32;
        const int tx = t & 31, ty = t >> 5;      // 32x32
        tile[ty][tx] = W[(size_t)(r0 + ty) * 768 + c0 + tx];
        __syncthreads();
        T[(size_t)(c0 + ty) * 768 + r0 + tx] = f32_to_bf16(tile[tx][ty]);
    }
}

// ---------------------------------------------------------------------------
// qk2: Q and K in ONE exact-fill launch. C = Xbf[8192,768] . Wqk^T, where
// Wqk = WqT||WkT stacked rows [1536,768] (contiguous allocations).
// v4 monolithic core, BM=256 x BN=192, NT=12, ring-2 LDS (112 KiB),
// counted vmcnt(7). 256 blocks = 32 mb x 8 nb; nb 0-3 -> Qb, 4-7 -> Kb.
// XCD swizzle: mb = xcd*4 + (local>>3), nb = local&7 -> A panels L2-shared 8x.
// ---------------------------------------------------------------------------
__global__ __launch_bounds__(512) void qk2(
    const unsigned short* __restrict__ Xbf,
    const unsigned short* __restrict__ Wqk,
    unsigned short* __restrict__ Qb,
    unsigned short* __restrict__ Kb)
{
    const int f = blockIdx.x;           // 0..255
    const int xcd = f & 7;
    const int local = f >> 3;           // 0..31
    const int mb = xcd * 4 + (local >> 3);   // 0..31
    const int nb = local & 7;                // 0..7
    const unsigned short* A = Xbf;
    const unsigned short* B = Wqk;
    unsigned short* C = (nb < 4) ? Qb : Kb;
    const int m0 = mb * 256;
    const int n0 = nb * 192;            // row into Wqk (0..1344)
    const int c0 = (nb & 3) * 192;      // col into Qb/Kb
    const int lda = 768, ldb = 768, ldc = 768;
    constexpr int NT = 12;

    __shared__ unsigned short As[2][256 * 64];
    __shared__ unsigned short Bs[2][192 * 64];

    const int t = threadIdx.x;
    const int lane = t & 63;
    const int w = t >> 6;
    const int wm = (w >> 2) * 128;      // 0/128 (8 mi frags)
    const int wn = (w & 3) * 48;        // 0..144 (3 ni frags)
    const int r15 = lane & 15;
    const int qa = lane >> 4;

    const unsigned short* srcA[4];
    int dstA[4];
#pragma unroll
    for (int i = 0; i < 4; ++i) {
        const int c = i * 512 + t;
        const int row = c >> 3;
        const int cc = (c & 7) ^ (row & 7);
        srcA[i] = A + (size_t)(m0 + row) * lda + cc * 8;
        dstA[i] = c * 8;
    }
    const unsigned short* srcB[3];
    int dstB[3];
#pragma unroll
    for (int i = 0; i < 3; ++i) {
        const int c = i * 512 + t;
        const int row = c >> 3;
        const int cc = (c & 7) ^ (row & 7);
        srcB[i] = B + (size_t)(n0 + row) * ldb + cc * 8;
        dstB[i] = c * 8;
    }

    auto stage = [&](int buf, int kbase) {
#pragma unroll
        for (int i = 0; i < 4; ++i) load16(srcA[i] + kbase, &As[buf][dstA[i]]);
#pragma unroll
        for (int i = 0; i < 3; ++i) load16(srcB[i] + kbase, &Bs[buf][dstB[i]]);
    };

    int offA[8][2], offB[3][2];
#pragma unroll
    for (int mi = 0; mi < 8; ++mi) {
        const int row = wm + mi * 16 + r15;
#pragma unroll
        for (int ks = 0; ks < 2; ++ks)
            offA[mi][ks] = row * 64 + (((ks << 2) + qa) ^ (row & 7)) * 8;
    }
#pragma unroll
    for (int ni = 0; ni < 3; ++ni) {
        const int row = wn + ni * 16 + r15;
#pragma unroll
        for (int ks = 0; ks < 2; ++ks)
            offB[ni][ks] = row * 64 + (((ks << 2) + qa) ^ (row & 7)) * 8;
    }

    f32x4 acc[8][3];
#pragma unroll
    for (int i = 0; i < 8; ++i)
#pragma unroll
        for (int j = 0; j < 3; ++j) acc[i][j] = (f32x4){0.f, 0.f, 0.f, 0.f};

    stage(0, 0);
    stage(1, 64);

    for (int tt = 0; tt < NT; ++tt) {
        const int b = tt & 1;
        if (tt == NT - 1) {
            asm volatile("s_waitcnt vmcnt(0)" ::: "memory");
        } else {
            asm volatile("s_waitcnt vmcnt(7)" ::: "memory");
        }
        __builtin_amdgcn_s_barrier();

#pragma unroll
        for (int ks = 0; ks < 2; ++ks) {
            bf16x8 aA[8], bB[3];
#pragma unroll
            for (int i = 0; i < 8; ++i)
                aA[i] = *(const bf16x8*)&As[b][offA[i][ks]];
#pragma unroll
            for (int ni = 0; ni < 3; ++ni)
                bB[ni] = *(const bf16x8*)&Bs[b][offB[ni][ks]];
#pragma unroll
            for (int i = 0; i < 8; ++i)
#pragma unroll
                for (int ni = 0; ni < 3; ++ni)
                    acc[i][ni] = __builtin_amdgcn_mfma_f32_16x16x32_bf16(
                        aA[i], bB[ni], acc[i][ni], 0, 0, 0);
        }

        asm volatile("" ::: "memory");
        __builtin_amdgcn_s_barrier();

        if (tt + 2 < NT) stage(b, (tt + 2) << 6);
    }

    const int cr = (lane >> 4) * 4;
#pragma unroll
    for (int mi = 0; mi < 8; ++mi)
#pragma unroll
        for (int ni = 0; ni < 3; ++ni) {
            const int gm = m0 + wm + mi * 16 + cr;
            const int gn = c0 + wn + ni * 16 + r15;
#pragma unroll
            for (int r = 0; r < 4; ++r)
                C[(size_t)(gm + r) * ldc + gn] = f32_to_bf16(acc[mi][ni][r]);
        }
}

// ---------------------------------------------------------------------------
// vt2: V^T = WvT[768,768] . Xbf^T -> [768, 8192]. v4 core, BM=192 x BN=128,
// NT=12, ring-2 LDS (80 KiB), counted vmcnt(5). 256 blocks = 4 mb x 64 nb =
// exact fill. XCD swizzle: nb = xcd*8 + (local>>2), mb = local&3 -> Xbf
// panels L2-shared 4x.
// ---------------------------------------------------------------------------
__global__ __launch_bounds__(512) void vt2(
    const unsigned short* __restrict__ WvT,
    const unsigned short* __restrict__ Xbf,
    unsigned short* __restrict__ Vt)
{
    const int f = blockIdx.x;           // 0..255
    const int xcd = f & 7;
    const int local = f >> 3;           // 0..31
    const int nb = xcd * 8 + (local >> 2);   // 0..63
    const int mb = local & 3;                // 0..3
    const unsigned short* A = WvT;
    const unsigned short* B = Xbf;
    unsigned short* C = Vt;
    const int m0 = mb * 192;
    const int n0 = nb * 128;
    const int lda = 768, ldb = 768, ldc = 8192;
    constexpr int NT = 12;

    __shared__ unsigned short As[2][192 * 64];
    __shared__ unsigned short Bs[2][128 * 64];

    const int t = threadIdx.x;
    const int lane = t & 63;
    const int w = t >> 6;
    const int wm = (w >> 2) * 96;       // 0/96 (6 mi frags)
    const int wn = (w & 3) * 32;        // 0..96 (2 ni frags)
    const int r15 = lane & 15;
    const int qa = lane >> 4;

    const unsigned short* srcA[3];
    int dstA[3];
#pragma unroll
    for (int i = 0; i < 3; ++i) {
        const int c = i * 512 + t;
        const int row = c >> 3;
        const int cc = (c & 7) ^ (row & 7);
        srcA[i] = A + (size_t)(m0 + row) * lda + cc * 8;
        dstA[i] = c * 8;
    }
    const unsigned short* srcB[2];
    int dstB[2];
#pragma unroll
    for (int i = 0; i < 2; ++i) {
        const int c = i * 512 + t;
        const int row = c >> 3;
        const int cc = (c & 7) ^ (row & 7);
        srcB[i] = B + (size_t)(n0 + row) * ldb + cc * 8;
        dstB[i] = c * 8;
    }

    auto stage = [&](int buf, int kbase) {
#pragma unroll
        for (int i = 0; i < 3; ++i) load16(srcA[i] + kbase, &As[buf][dstA[i]]);
#pragma unroll
        for (int i = 0; i < 2; ++i) load16(srcB[i] + kbase, &Bs[buf][dstB[i]]);
    };

    int offA[6][2], offB[2][2];
#pragma unroll
    for (int mi = 0; mi < 6; ++mi) {
        const int row = wm + mi * 16 + r15;
#pragma unroll
        for (int ks = 0; ks < 2; ++ks)
            offA[mi][ks] = row * 64 + (((ks << 2) + qa) ^ (row & 7)) * 8;
    }
#pragma unroll
    for (int ni = 0; ni < 2; ++ni) {
        const int row = wn + ni * 16 + r15;
#pragma unroll
        for (int ks = 0; ks < 2; ++ks)
            offB[ni][ks] = row * 64 + (((ks << 2) + qa) ^ (row & 7)) * 8;
    }

    f32x4 acc[6][2];
#pragma unroll
    for (int i = 0; i < 6; ++i)
#pragma unroll
        for (int j = 0; j < 2; ++j) acc[i][j] = (f32x4){0.f, 0.f, 0.f, 0.f};

    stage(0, 0);
    stage(1, 64);

    for (int tt = 0; tt < NT; ++tt) {
        const int b = tt & 1;
        if (tt == NT - 1) {
            asm volatile("s_waitcnt vmcnt(0)" ::: "memory");
        } else {
            asm volatile("s_waitcnt vmcnt(5)" ::: "memory");
        }
        __builtin_amdgcn_s_barrier();

#pragma unroll
        for (int ks = 0; ks < 2; ++ks) {
            bf16x8 aA[6], bB[2];
#pragma unroll
            for (int i = 0; i < 6; ++i)
                aA[i] = *(const bf16x8*)&As[b][offA[i][ks]];
#pragma unroll
            for (int ni = 0; ni < 2; ++ni)
                bB[ni] = *(const bf16x8*)&Bs[b][offB[ni][ks]];
#pragma unroll
            for (int i = 0; i < 6; ++i)
#pragma unroll
                for (int ni = 0; ni < 2; ++ni)
                    acc[i][ni] = __builtin_amdgcn_mfma_f32_16x16x32_bf16(
                        aA[i], bB[ni], acc[i][ni], 0, 0, 0);
        }

        asm volatile("" ::: "memory");
        __builtin_amdgcn_s_barrier();

        if (tt + 2 < NT) stage(b, (tt + 2) << 6);
    }

    const int cr = (lane >> 4) * 4;
#pragma unroll
    for (int mi = 0; mi < 6; ++mi)
#pragma unroll
        for (int ni = 0; ni < 2; ++ni) {
            const int gm = m0 + wm + mi * 16 + cr;
            const int gn = n0 + wn + ni * 16 + r15;
#pragma unroll
            for (int r = 0; r < 4; ++r)
                C[(size_t)(gm + r) * ldc + gn] = f32_to_bf16(acc[mi][ni][r]);
        }
}

// ---------------------------------------------------------------------------
// Sexp = exp(alpha * Q.K^T) bf16, 256^2 v4 core (monolithic body, ring-2 LDS,
// counted vmcnt, 2 barriers/tile, XCD swizzle). STORE-ONLY epilogue -- the
// R4 form measured at 60.6 us. All fused-lsum variants cost +17-20 us
// (R5/R9: register spill at the compiler's 128-VGPR budget; R7: L2-evicted
// readback). The denominator lives in the dedicated rowsum kernel instead.
// ---------------------------------------------------------------------------
__global__ __launch_bounds__(512) void gemm_s_exp2(
    const unsigned short* __restrict__ Q, const unsigned short* __restrict__ Kb,
    unsigned short* __restrict__ Sexp, float alpha)
{
    const int f = blockIdx.x;            // 0..511
    const int xcd = f & 7;
    const int local = f >> 3;            // 0..63
    const int x = (xcd & 1) * 8 + (local & 7);
    const int y = ((xcd >> 1) & 1) * 8 + (local >> 3);
    const int bb = xcd >> 2;
    const unsigned short* A = Q + (size_t)bb * 3145728;
    const unsigned short* B = Kb + (size_t)bb * 3145728;
    unsigned short* C = Sexp + (size_t)bb * 16777216;
    const int m0 = y * 256, n0 = x * 256;
    const int lda = 768, ldb = 768, ldc = 4096;
    constexpr int NT = 12;

    __shared__ unsigned short As[2][256 * 64];
    __shared__ unsigned short Bs[2][256 * 64];

    const int t = threadIdx.x;          // 0..511
    const int lane = t & 63;
    const int w = t >> 6;               // 0..7
    const int wm = (w >> 2) * 128;      // 0 / 128
    const int wn = (w & 3) * 64;        // 0..192
    const int r15 = lane & 15;
    const int qa = lane >> 4;           // 0..3

    const unsigned short* srcA[4];
    const unsigned short* srcB[4];
    int dst[4];
#pragma unroll
    for (int i = 0; i < 4; ++i) {
        const int c = i * 512 + t;
        const int row = c >> 3;
        const int cc = (c & 7) ^ (row & 7);
        srcA[i] = A + (size_t)(m0 + row) * lda + cc * 8;
        srcB[i] = B + (size_t)(n0 + row) * ldb + cc * 8;
        dst[i] = c * 8;
    }

    auto stage = [&](int buf, int kbase) {
#pragma unroll
        for (int i = 0; i < 4; ++i)
            load16(srcA[i] + kbase, &As[buf][dst[i]]);
#pragma unroll
        for (int i = 0; i < 4; ++i)
            load16(srcB[i] + kbase, &Bs[buf][dst[i]]);
    };

    int offA[8][2], offB[4][2];
#pragma unroll
    for (int mi = 0; mi < 8; ++mi) {
        const int row = wm + mi * 16 + r15;
#pragma unroll
        for (int ks = 0; ks < 2; ++ks)
            offA[mi][ks] = row * 64 + (((ks << 2) + qa) ^ (row & 7)) * 8;
    }
#pragma unroll
    for (int ni = 0; ni < 4; ++ni) {
        const int row = wn + ni * 16 + r15;
#pragma unroll
        for (int ks = 0; ks < 2; ++ks)
            offB[ni][ks] = row * 64 + (((ks << 2) + qa) ^ (row & 7)) * 8;
    }

    f32x4 acc[8][4];
#pragma unroll
    for (int i = 0; i < 8; ++i)
#pragma unroll
        for (int j = 0; j < 4; ++j) acc[i][j] = (f32x4){0.f, 0.f, 0.f, 0.f};

    stage(0, 0);
    stage(1, 64);

    for (int tt = 0; tt < NT; ++tt) {
        const int b = tt & 1;
        if (tt == NT - 1) {
            asm volatile("s_waitcnt vmcnt(0)" ::: "memory");
        } else {
            asm volatile("s_waitcnt vmcnt(8)" ::: "memory");
        }
        __builtin_amdgcn_s_barrier();

#pragma unroll
        for (int ks = 0; ks < 2; ++ks) {
            bf16x8 aA[8], bB[4];
#pragma unroll
            for (int i = 0; i < 8; ++i)
                aA[i] = *(const bf16x8*)&As[b][offA[i][ks]];
#pragma unroll
            for (int ni = 0; ni < 4; ++ni)
                bB[ni] = *(const bf16x8*)&Bs[b][offB[ni][ks]];
#pragma unroll
            for (int i = 0; i < 8; ++i)
#pragma unroll
                for (int ni = 0; ni < 4; ++ni)
                    acc[i][ni] = __builtin_amdgcn_mfma_f32_16x16x32_bf16(
                        aA[i], bB[ni], acc[i][ni], 0, 0, 0);
        }

        asm volatile("" ::: "memory");
        __builtin_amdgcn_s_barrier();

        if (tt + 2 < NT) stage(b, (tt + 2) << 6);
    }

    // store-only epilogue (low register pressure)
    const int cr = (lane >> 4) * 4;
#pragma unroll
    for (int mi = 0; mi < 8; ++mi)
#pragma unroll
        for (int ni = 0; ni < 4; ++ni) {
            const int gm = m0 + wm + mi * 16 + cr;
            const int gn = n0 + wn + ni * 16 + r15;
#pragma unroll
            for (int r = 0; r < 4; ++r)
                C[(size_t)(gm + r) * ldc + gn] =
                    f32_to_bf16(__expf(alpha * acc[mi][ni][r]));
        }
}

// ---------------------------------------------------------------------------
// rowsum: lsum[row] = sum of Sexp[row][:]. One WAVE per row (4 rows/block),
// coalesced us8 loads (64 lanes x 8 chunks = 4096 elems), 64-lane shfl
// reduce, single plain store (no atomics). 2048 blocks, ~67 MB streamed
// at HBM rate ~= 11 us.
// ---------------------------------------------------------------------------
__global__ __launch_bounds__(256) void rowsum(
    const unsigned short* __restrict__ Sexp, float* __restrict__ lsum)
{
    const int w = threadIdx.x >> 6;           // 0..3
    const int lane = threadIdx.x & 63;
    const int row = blockIdx.x * 4 + w;       // 0..8191 == batch*4096 + r
    const unsigned short* rp = Sexp + (size_t)row * 4096;
    float s = 0.f;
#pragma unroll
    for (int i = 0; i < 8; ++i) {
        us8 v = ((const us8*)rp)[lane + i * 64];
#pragma unroll
        for (int j = 0; j < 8; ++j) s += bf16_to_f32(v[j]);
    }
#pragma unroll
    for (int off = 32; off > 0; off >>= 1) s += __shfl_down(s, off, 64);
    if (lane == 0) lsum[row] = s;
}

// ---------------------------------------------------------------------------
// Fused O-GEMM + normalize: out = (Sexp . V) / lsum, fp32. 24 MFMA/tile.
// BM=128 x BN=192 -> 256 blocks exact fill. Ring-3 LDS, counted vmcnt(10/5/0).
// Row-sharing XCD swizzle (FETCH 57 MB measured in R8).
// ---------------------------------------------------------------------------
__global__ __launch_bounds__(512) void gemm_out(
    const unsigned short* __restrict__ P, const unsigned short* __restrict__ Vt,
    const float* __restrict__ lsum, float* __restrict__ out)
{
    const int f = blockIdx.x;           // 0..255
    const int xcd = f & 7;
    const int local = f >> 3;           // 0..31
    const int nb = local & 3;           // n-block (same XCD for all 4)
    const int rg = xcd * 8 + (local >> 2);   // row group 0..63
    const int batch = rg >> 5;
    const int mb = rg & 31;             // m-block 0..31
    const unsigned short* A = P + (size_t)batch * 16777216;
    const unsigned short* B = Vt + (size_t)batch * 4096;
    const float* ls = lsum + batch * 4096;
    float* C = out + (size_t)batch * 3145728;
    const int m0 = mb * 128, n0 = nb * 192;
    const int lda = 4096, ldb = 8192;
    constexpr int NT = 64;

    __shared__ unsigned short As[3][128 * 64];
    __shared__ unsigned short Bs[3][192 * 64];

    const int t = threadIdx.x;          // 0..511
    const int lane = t & 63;
    const int w = t >> 6;               // 0..7
    const int wm = (w >> 2) * 64;       // 0 / 64
    const int wn = (w & 3) * 48;        // 0..144
    const int r15 = lane & 15;
    const int qa = lane >> 4;           // 0..3

    const unsigned short* srcA[2];
    int dstA[2];
#pragma unroll
    for (int i = 0; i < 2; ++i) {
        const int c = i * 512 + t;
        const int row = c >> 3;
        const int cc = (c & 7) ^ (row & 7);
        srcA[i] = A + (size_t)(m0 + row) * lda + cc * 8;
        dstA[i] = c * 8;
    }
    const unsigned short* srcB[3];
    int dstB[3];
#pragma unroll
    for (int i = 0; i < 3; ++i) {
        const int c = i * 512 + t;
        const int row = c >> 3;
        const int cc = (c & 7) ^ (row & 7);
        srcB[i] = B + (size_t)(n0 + row) * ldb + cc * 8;
        dstB[i] = c * 8;
    }

    auto stage = [&](int buf, int kbase) {
#pragma unroll
        for (int i = 0; i < 2; ++i)
            load16(srcA[i] + kbase, &As[buf][dstA[i]]);
#pragma unroll
        for (int i = 0; i < 3; ++i)
            load16(srcB[i] + kbase, &Bs[buf][dstB[i]]);
    };

    int offA[4][2], offB[3][2];
#pragma unroll
    for (int mi = 0; mi < 4; ++mi) {
        const int row = wm + mi * 16 + r15;
#pragma unroll
        for (int ks = 0; ks < 2; ++ks)
            offA[mi][ks] = row * 64 + (((ks << 2) + qa) ^ (row & 7)) * 8;
    }
#pragma unroll
    for (int ni = 0; ni < 3; ++ni) {
        const int row = wn + ni * 16 + r15;
#pragma unroll
        for (int ks = 0; ks < 2; ++ks)
            offB[ni][ks] = row * 64 + (((ks << 2) + qa) ^ (row & 7)) * 8;
    }

    f32x4 acc[4][3];
#pragma unroll
    for (int i = 0; i < 4; ++i)
#pragma unroll
        for (int j = 0; j < 3; ++j) acc[i][j] = (f32x4){0.f, 0.f, 0.f, 0.f};

    stage(0, 0);
    stage(1, 64);
    stage(2, 128);

    int b = 0;
    for (int tt = 0; tt < NT; ++tt) {
        if (tt < NT - 2) {
            asm volatile("s_waitcnt vmcnt(10)" ::: "memory");
        } else if (tt == NT - 2) {
            asm volatile("s_waitcnt vmcnt(5)" ::: "memory");
        } else {
            asm volatile("s_waitcnt vmcnt(0)" ::: "memory");
        }
        __builtin_amdgcn_s_barrier();

#pragma unroll
        for (int ks = 0; ks < 2; ++ks) {
            bf16x8 aA[4], bB[3];
#pragma unroll
            for (int i = 0; i < 4; ++i)
                aA[i] = *(const bf16x8*)&As[b][offA[i][ks]];
#pragma unroll
            for (int ni = 0; ni < 3; ++ni)
                bB[ni] = *(const bf16x8*)&Bs[b][offB[ni][ks]];
#pragma unroll
            for (int i = 0; i < 4; ++i)
#pragma unroll
                for (int ni = 0; ni < 3; ++ni)
                    acc[i][ni] = __builtin_amdgcn_mfma_f32_16x16x32_bf16(
                        aA[i], bB[ni], acc[i][ni], 0, 0, 0);
        }

        asm volatile("" ::: "memory");
        __builtin_amdgcn_s_barrier();

        if (tt + 3 < NT) stage(b, (tt + 3) << 6);
        b = (b == 2) ? 0 : b + 1;
    }

    // epilogue: divide by denominator, write fp32 out
    const int cr = (lane >> 4) * 4;
#pragma unroll
    for (int mi = 0; mi < 4; ++mi) {
        const int gm = m0 + wm + mi * 16 + cr;
        const float i0 = 1.f / ls[gm + 0];
        const float i1 = 1.f / ls[gm + 1];
        const float i2 = 1.f / ls[gm + 2];
        const float i3 = 1.f / ls[gm + 3];
#pragma unroll
        for (int ni = 0; ni < 3; ++ni) {
            const int gn = n0 + wn + ni * 16 + r15;
            C[(size_t)(gm + 0) * 768 + gn] = acc[mi][ni][0] * i0;
            C[(size_t)(gm + 1) * 768 + gn] = acc[mi][ni][1] * i1;
            C[(size_t)(gm + 2) * 768 + gn] = acc[mi][ni][2] * i2;
            C[(size_t)(gm + 3) * 768 + gn] = acc[mi][ni][3] * i3;
        }
    }
}

// ---------------------------------------------------------------------------
extern "C" void kernel_launch(void* const* d_in, const int* in_sizes, int n_in,
                              void* d_out, int out_size, void* d_ws, size_t ws_size,
                              hipStream_t stream) {
    const float* x  = (const float*)d_in[0];   // [2,4096,768]
    const float* Wq = (const float*)d_in[1];   // [768,768]
    const float* Wk = (const float*)d_in[2];
    const float* Wv = (const float*)d_in[3];
    float* out = (float*)d_out;                // [2,4096,768] fp32

    char* base = (char*)d_ws;
    size_t off = 0;
    auto alloc = [&](size_t b) { char* p = base + off; off += (b + 255) & ~(size_t)255; return p; };

    unsigned short* Xbf = (unsigned short*)alloc(8192ull * 768 * 2);   // x as bf16
    unsigned short* WqT = (unsigned short*)alloc(768ull * 768 * 2);    // W^T bf16, x3 contiguous
    unsigned short* WkT = (unsigned short*)alloc(768ull * 768 * 2);
    unsigned short* WvT = (unsigned short*)alloc(768ull * 768 * 2);
    unsigned short* Qb  = (unsigned short*)alloc(8192ull * 768 * 2);   // Q bf16
    unsigned short* Kb  = (unsigned short*)alloc(8192ull * 768 * 2);   // K bf16
    unsigned short* Vt  = (unsigned short*)alloc(768ull * 8192 * 2);   // V^T bf16 [768,8192]
    unsigned short* Sexp = (unsigned short*)alloc(2ull * 4096 * 4096 * 2); // exp(scores) bf16
    float* lsum = (float*)alloc(2ull * 4096 * 4);                      // softmax denominators
    (void)ws_size; (void)in_sizes; (void)n_in; (void)out_size; (void)WkT; (void)WvT;

    // 1) x -> bf16, W -> W^T bf16
    prep<<<dim3(3264), dim3(1024), 0, stream>>>(x, Xbf, Wq, Wk, Wv, WqT, WkT, WvT);
    // 2) Q and K in one exact-fill 256-block launch (B = WqT||WkT stacked)
    qk2<<<dim3(256), dim3(512), 0, stream>>>(Xbf, WqT, Qb, Kb);
    // 3) V^T, 256 blocks exact fill
    vt2<<<dim3(256), dim3(512), 0, stream>>>(WvT, Xbf, Vt);
    // 4) Sexp = exp(Q.K^T / sqrt(768)) bf16, store-only epilogue (R4 form)
    gemm_s_exp2<<<dim3(512), dim3(512), 0, stream>>>(
        Qb, Kb, Sexp, 0.03608439182435161f);
    // 5) lsum = rowsum(Sexp) -- 1 wave/row, no atomics, ~11 us
    rowsum<<<dim3(2048), dim3(256), 0, stream>>>(Sexp, lsum);
    // 6) out = (Sexp . V) / lsum, fp32
    gemm_out<<<dim3(256), dim3(512), 0, stream>>>(Sexp, Vt, lsum, out);
}

// Round 11
// 248.445 us; speedup vs baseline: 1.0385x; 1.0385x over previous
//
#include <hip/hip_runtime.h>

typedef __bf16 bf16x8 __attribute__((ext_vector_type(8)));
typedef float f32x4 __attribute__((ext_vector_type(4)));
typedef unsigned short us8 __attribute__((ext_vector_type(8)));

#define GAS __attribute__((address_space(1)))
#define LAS __attribute__((address_space(3)))

__device__ __forceinline__ unsigned short f32_to_bf16(float f) {
    unsigned int u = __float_as_uint(f);
    u += 0x7FFFu + ((u >> 16) & 1u);   // round-to-nearest-even
    return (unsigned short)(u >> 16);
}

__device__ __forceinline__ float bf16_to_f32(unsigned short h) {
    return __uint_as_float((unsigned int)h << 16);
}

__device__ __forceinline__ void load16(const unsigned short* g, unsigned short* l) {
    // async global->LDS, 16B per lane; LDS dest is wave-uniform base + lane*16
    __builtin_amdgcn_global_load_lds((GAS unsigned int*)g, (LAS unsigned int*)l, 16, 0, 0);
}

// ---------------------------------------------------------------------------
// prep (1024 threads): blocks [0,1536) convert x fp32->bf16 float4-wide;
// blocks [1536,3264) transpose the three 768x768 weights to bf16.
// ---------------------------------------------------------------------------
__global__ __launch_bounds__(1024) void prep(
    const float* __restrict__ x, unsigned short* __restrict__ Xbf,
    const float* __restrict__ W0, const float* __restrict__ W1, const float* __restrict__ W2,
    unsigned short* __restrict__ T0, unsigned short* __restrict__ T1, unsigned short* __restrict__ T2)
{
    __shared__ float tile[32][33];
    const int id = blockIdx.x;
    const int t = threadIdx.x;
    if (id < 1536) {
        int i = id * 1024 + t;
        float4 v = ((const float4*)x)[i];
        ushort4 o;
        o.x = f32_to_bf16(v.x); o.y = f32_to_bf16(v.y);
        o.z = f32_to_bf16(v.z); o.w = f32_to_bf16(v.w);
        ((ushort4*)Xbf)[i] = o;
    } else {
        const int tid = id - 1536;               // 0..1727
        const int z = tid / 576, rem = tid % 576;
        const int by = rem / 24, bx = rem % 24;
        const float* W = (z == 0) ? W0 : (z == 1) ? W1 : W2;
        unsigned short* T = (z == 0) ? T0 : (z == 1) ? T1 : T2;
        const int r0 = by * 32, c0 = bx * 32;
        const int tx = t & 31, ty = t >> 5;      // 32x32
        tile[ty][tx] = W[(size_t)(r0 + ty) * 768 + c0 + tx];
        __syncthreads();
        T[(size_t)(c0 + ty) * 768 + r0 + tx] = f32_to_bf16(tile[tx][ty]);
    }
}

// ---------------------------------------------------------------------------
// qk body: C = Xbf[8192,768] . Wqk^T, Wqk = WqT||WkT stacked [1536,768].
// v4 core, BM=256 x BN=192, NT=12, ring-2, counted vmcnt(7). f in [0,256).
// smem carve: As 2x16384, Bs 2x12288 shorts (112 KiB total).
// ---------------------------------------------------------------------------
__device__ __forceinline__ void qk_body(
    unsigned short* smem, int f,
    const unsigned short* __restrict__ Xbf, const unsigned short* __restrict__ Wqk,
    unsigned short* __restrict__ Qb, unsigned short* __restrict__ Kb)
{
    const int xcd = f & 7;
    const int local = f >> 3;           // 0..31
    const int mb = xcd * 4 + (local >> 3);   // 0..31
    const int nb = local & 7;                // 0..7
    unsigned short* AsP[2] = { smem, smem + 16384 };
    unsigned short* BsP[2] = { smem + 32768, smem + 32768 + 12288 };
    const unsigned short* A = Xbf;
    const unsigned short* B = Wqk;
    unsigned short* C = (nb < 4) ? Qb : Kb;
    const int m0 = mb * 256;
    const int n0 = nb * 192;
    const int c0 = (nb & 3) * 192;
    const int lda = 768, ldb = 768, ldc = 768;
    constexpr int NT = 12;

    const int t = threadIdx.x;
    const int lane = t & 63;
    const int w = t >> 6;
    const int wm = (w >> 2) * 128;
    const int wn = (w & 3) * 48;
    const int r15 = lane & 15;
    const int qa = lane >> 4;

    const unsigned short* srcA[4];
    int dstA[4];
#pragma unroll
    for (int i = 0; i < 4; ++i) {
        const int c = i * 512 + t;
        const int row = c >> 3;
        const int cc = (c & 7) ^ (row & 7);
        srcA[i] = A + (size_t)(m0 + row) * lda + cc * 8;
        dstA[i] = c * 8;
    }
    const unsigned short* srcB[3];
    int dstB[3];
#pragma unroll
    for (int i = 0; i < 3; ++i) {
        const int c = i * 512 + t;
        const int row = c >> 3;
        const int cc = (c & 7) ^ (row & 7);
        srcB[i] = B + (size_t)(n0 + row) * ldb + cc * 8;
        dstB[i] = c * 8;
    }

    auto stage = [&](int buf, int kbase) {
#pragma unroll
        for (int i = 0; i < 4; ++i) load16(srcA[i] + kbase, &AsP[buf][dstA[i]]);
#pragma unroll
        for (int i = 0; i < 3; ++i) load16(srcB[i] + kbase, &BsP[buf][dstB[i]]);
    };

    int offA[8][2], offB[3][2];
#pragma unroll
    for (int mi = 0; mi < 8; ++mi) {
        const int row = wm + mi * 16 + r15;
#pragma unroll
        for (int ks = 0; ks < 2; ++ks)
            offA[mi][ks] = row * 64 + (((ks << 2) + qa) ^ (row & 7)) * 8;
    }
#pragma unroll
    for (int ni = 0; ni < 3; ++ni) {
        const int row = wn + ni * 16 + r15;
#pragma unroll
        for (int ks = 0; ks < 2; ++ks)
            offB[ni][ks] = row * 64 + (((ks << 2) + qa) ^ (row & 7)) * 8;
    }

    f32x4 acc[8][3];
#pragma unroll
    for (int i = 0; i < 8; ++i)
#pragma unroll
        for (int j = 0; j < 3; ++j) acc[i][j] = (f32x4){0.f, 0.f, 0.f, 0.f};

    stage(0, 0);
    stage(1, 64);

    for (int tt = 0; tt < NT; ++tt) {
        const int b = tt & 1;
        if (tt == NT - 1) {
            asm volatile("s_waitcnt vmcnt(0)" ::: "memory");
        } else {
            asm volatile("s_waitcnt vmcnt(7)" ::: "memory");
        }
        __builtin_amdgcn_s_barrier();

#pragma unroll
        for (int ks = 0; ks < 2; ++ks) {
            bf16x8 aA[8], bB[3];
#pragma unroll
            for (int i = 0; i < 8; ++i)
                aA[i] = *(const bf16x8*)&AsP[b][offA[i][ks]];
#pragma unroll
            for (int ni = 0; ni < 3; ++ni)
                bB[ni] = *(const bf16x8*)&BsP[b][offB[ni][ks]];
#pragma unroll
            for (int i = 0; i < 8; ++i)
#pragma unroll
                for (int ni = 0; ni < 3; ++ni)
                    acc[i][ni] = __builtin_amdgcn_mfma_f32_16x16x32_bf16(
                        aA[i], bB[ni], acc[i][ni], 0, 0, 0);
        }

        asm volatile("" ::: "memory");
        __builtin_amdgcn_s_barrier();

        if (tt + 2 < NT) stage(b, (tt + 2) << 6);
    }

    const int cr = (lane >> 4) * 4;
#pragma unroll
    for (int mi = 0; mi < 8; ++mi)
#pragma unroll
        for (int ni = 0; ni < 3; ++ni) {
            const int gm = m0 + wm + mi * 16 + cr;
            const int gn = c0 + wn + ni * 16 + r15;
#pragma unroll
            for (int r = 0; r < 4; ++r)
                C[(size_t)(gm + r) * ldc + gn] = f32_to_bf16(acc[mi][ni][r]);
        }
}

// ---------------------------------------------------------------------------
// vt body: V^T = WvT[768,768] . Xbf^T -> [768,8192]. v4 core, BM=192 x
// BN=128, NT=12, ring-2, counted vmcnt(5). f in [0,256).
// smem carve: As 2x12288, Bs 2x8192 shorts (80 KiB of the 112).
// ---------------------------------------------------------------------------
__device__ __forceinline__ void vt_body(
    unsigned short* smem, int f,
    const unsigned short* __restrict__ WvT, const unsigned short* __restrict__ Xbf,
    unsigned short* __restrict__ Vt)
{
    const int xcd = f & 7;
    const int local = f >> 3;           // 0..31
    const int nb = xcd * 8 + (local >> 2);   // 0..63
    const int mb = local & 3;                // 0..3
    unsigned short* AsP[2] = { smem, smem + 12288 };
    unsigned short* BsP[2] = { smem + 24576, smem + 24576 + 8192 };
    const unsigned short* A = WvT;
    const unsigned short* B = Xbf;
    unsigned short* C = Vt;
    const int m0 = mb * 192;
    const int n0 = nb * 128;
    const int lda = 768, ldb = 768, ldc = 8192;
    constexpr int NT = 12;

    const int t = threadIdx.x;
    const int lane = t & 63;
    const int w = t >> 6;
    const int wm = (w >> 2) * 96;
    const int wn = (w & 3) * 32;
    const int r15 = lane & 15;
    const int qa = lane >> 4;

    const unsigned short* srcA[3];
    int dstA[3];
#pragma unroll
    for (int i = 0; i < 3; ++i) {
        const int c = i * 512 + t;
        const int row = c >> 3;
        const int cc = (c & 7) ^ (row & 7);
        srcA[i] = A + (size_t)(m0 + row) * lda + cc * 8;
        dstA[i] = c * 8;
    }
    const unsigned short* srcB[2];
    int dstB[2];
#pragma unroll
    for (int i = 0; i < 2; ++i) {
        const int c = i * 512 + t;
        const int row = c >> 3;
        const int cc = (c & 7) ^ (row & 7);
        srcB[i] = B + (size_t)(n0 + row) * ldb + cc * 8;
        dstB[i] = c * 8;
    }

    auto stage = [&](int buf, int kbase) {
#pragma unroll
        for (int i = 0; i < 3; ++i) load16(srcA[i] + kbase, &AsP[buf][dstA[i]]);
#pragma unroll
        for (int i = 0; i < 2; ++i) load16(srcB[i] + kbase, &BsP[buf][dstB[i]]);
    };

    int offA[6][2], offB[2][2];
#pragma unroll
    for (int mi = 0; mi < 6; ++mi) {
        const int row = wm + mi * 16 + r15;
#pragma unroll
        for (int ks = 0; ks < 2; ++ks)
            offA[mi][ks] = row * 64 + (((ks << 2) + qa) ^ (row & 7)) * 8;
    }
#pragma unroll
    for (int ni = 0; ni < 2; ++ni) {
        const int row = wn + ni * 16 + r15;
#pragma unroll
        for (int ks = 0; ks < 2; ++ks)
            offB[ni][ks] = row * 64 + (((ks << 2) + qa) ^ (row & 7)) * 8;
    }

    f32x4 acc[6][2];
#pragma unroll
    for (int i = 0; i < 6; ++i)
#pragma unroll
        for (int j = 0; j < 2; ++j) acc[i][j] = (f32x4){0.f, 0.f, 0.f, 0.f};

    stage(0, 0);
    stage(1, 64);

    for (int tt = 0; tt < NT; ++tt) {
        const int b = tt & 1;
        if (tt == NT - 1) {
            asm volatile("s_waitcnt vmcnt(0)" ::: "memory");
        } else {
            asm volatile("s_waitcnt vmcnt(5)" ::: "memory");
        }
        __builtin_amdgcn_s_barrier();

#pragma unroll
        for (int ks = 0; ks < 2; ++ks) {
            bf16x8 aA[6], bB[2];
#pragma unroll
            for (int i = 0; i < 6; ++i)
                aA[i] = *(const bf16x8*)&AsP[b][offA[i][ks]];
#pragma unroll
            for (int ni = 0; ni < 2; ++ni)
                bB[ni] = *(const bf16x8*)&BsP[b][offB[ni][ks]];
#pragma unroll
            for (int i = 0; i < 6; ++i)
#pragma unroll
                for (int ni = 0; ni < 2; ++ni)
                    acc[i][ni] = __builtin_amdgcn_mfma_f32_16x16x32_bf16(
                        aA[i], bB[ni], acc[i][ni], 0, 0, 0);
        }

        asm volatile("" ::: "memory");
        __builtin_amdgcn_s_barrier();

        if (tt + 2 < NT) stage(b, (tt + 2) << 6);
    }

    const int cr = (lane >> 4) * 4;
#pragma unroll
    for (int mi = 0; mi < 6; ++mi)
#pragma unroll
        for (int ni = 0; ni < 2; ++ni) {
            const int gm = m0 + wm + mi * 16 + cr;
            const int gn = n0 + wn + ni * 16 + r15;
#pragma unroll
            for (int r = 0; r < 4; ++r)
                C[(size_t)(gm + r) * ldc + gn] = f32_to_bf16(acc[mi][ni][r]);
        }
}

// ---------------------------------------------------------------------------
// qkv3: Q, K and V^T in ONE launch (512 blocks, 2 exact rounds).
// blocks [0,256): qk path; [256,512): vt path. Shared 112 KiB smem carve.
// ---------------------------------------------------------------------------
__global__ __launch_bounds__(512) void qkv3(
    const unsigned short* __restrict__ Xbf,
    const unsigned short* __restrict__ Wqk,   // WqT||WkT||WvT contiguous
    unsigned short* __restrict__ Qb,
    unsigned short* __restrict__ Kb,
    unsigned short* __restrict__ Vt)
{
    __shared__ unsigned short smem[57344];    // 112 KiB
    const int f = blockIdx.x;
    if (f < 256) qk_body(smem, f, Xbf, Wqk, Qb, Kb);
    else         vt_body(smem, f - 256, Wqk + 1179648, Xbf, Vt);
}

// ---------------------------------------------------------------------------
// Sexp = exp(alpha * Q.K^T) bf16, 256^2 v4 core (monolithic body, ring-2 LDS,
// counted vmcnt, 2 barriers/tile, XCD swizzle). STORE-ONLY epilogue (the
// measured-fastest form; all fused-lsum variants cost +17-20 us).
// ---------------------------------------------------------------------------
__global__ __launch_bounds__(512) void gemm_s_exp2(
    const unsigned short* __restrict__ Q, const unsigned short* __restrict__ Kb,
    unsigned short* __restrict__ Sexp, float alpha)
{
    const int f = blockIdx.x;            // 0..511
    const int xcd = f & 7;
    const int local = f >> 3;            // 0..63
    const int x = (xcd & 1) * 8 + (local & 7);
    const int y = ((xcd >> 1) & 1) * 8 + (local >> 3);
    const int bb = xcd >> 2;
    const unsigned short* A = Q + (size_t)bb * 3145728;
    const unsigned short* B = Kb + (size_t)bb * 3145728;
    unsigned short* C = Sexp + (size_t)bb * 16777216;
    const int m0 = y * 256, n0 = x * 256;
    const int lda = 768, ldb = 768, ldc = 4096;
    constexpr int NT = 12;

    __shared__ unsigned short As[2][256 * 64];
    __shared__ unsigned short Bs[2][256 * 64];

    const int t = threadIdx.x;          // 0..511
    const int lane = t & 63;
    const int w = t >> 6;               // 0..7
    const int wm = (w >> 2) * 128;      // 0 / 128
    const int wn = (w & 3) * 64;        // 0..192
    const int r15 = lane & 15;
    const int qa = lane >> 4;           // 0..3

    const unsigned short* srcA[4];
    const unsigned short* srcB[4];
    int dst[4];
#pragma unroll
    for (int i = 0; i < 4; ++i) {
        const int c = i * 512 + t;
        const int row = c >> 3;
        const int cc = (c & 7) ^ (row & 7);
        srcA[i] = A + (size_t)(m0 + row) * lda + cc * 8;
        srcB[i] = B + (size_t)(n0 + row) * ldb + cc * 8;
        dst[i] = c * 8;
    }

    auto stage = [&](int buf, int kbase) {
#pragma unroll
        for (int i = 0; i < 4; ++i)
            load16(srcA[i] + kbase, &As[buf][dst[i]]);
#pragma unroll
        for (int i = 0; i < 4; ++i)
            load16(srcB[i] + kbase, &Bs[buf][dst[i]]);
    };

    int offA[8][2], offB[4][2];
#pragma unroll
    for (int mi = 0; mi < 8; ++mi) {
        const int row = wm + mi * 16 + r15;
#pragma unroll
        for (int ks = 0; ks < 2; ++ks)
            offA[mi][ks] = row * 64 + (((ks << 2) + qa) ^ (row & 7)) * 8;
    }
#pragma unroll
    for (int ni = 0; ni < 4; ++ni) {
        const int row = wn + ni * 16 + r15;
#pragma unroll
        for (int ks = 0; ks < 2; ++ks)
            offB[ni][ks] = row * 64 + (((ks << 2) + qa) ^ (row & 7)) * 8;
    }

    f32x4 acc[8][4];
#pragma unroll
    for (int i = 0; i < 8; ++i)
#pragma unroll
        for (int j = 0; j < 4; ++j) acc[i][j] = (f32x4){0.f, 0.f, 0.f, 0.f};

    stage(0, 0);
    stage(1, 64);

    for (int tt = 0; tt < NT; ++tt) {
        const int b = tt & 1;
        if (tt == NT - 1) {
            asm volatile("s_waitcnt vmcnt(0)" ::: "memory");
        } else {
            asm volatile("s_waitcnt vmcnt(8)" ::: "memory");
        }
        __builtin_amdgcn_s_barrier();

#pragma unroll
        for (int ks = 0; ks < 2; ++ks) {
            bf16x8 aA[8], bB[4];
#pragma unroll
            for (int i = 0; i < 8; ++i)
                aA[i] = *(const bf16x8*)&As[b][offA[i][ks]];
#pragma unroll
            for (int ni = 0; ni < 4; ++ni)
                bB[ni] = *(const bf16x8*)&Bs[b][offB[ni][ks]];
#pragma unroll
            for (int i = 0; i < 8; ++i)
#pragma unroll
                for (int ni = 0; ni < 4; ++ni)
                    acc[i][ni] = __builtin_amdgcn_mfma_f32_16x16x32_bf16(
                        aA[i], bB[ni], acc[i][ni], 0, 0, 0);
        }

        asm volatile("" ::: "memory");
        __builtin_amdgcn_s_barrier();

        if (tt + 2 < NT) stage(b, (tt + 2) << 6);
    }

    // store-only epilogue (low register pressure)
    const int cr = (lane >> 4) * 4;
#pragma unroll
    for (int mi = 0; mi < 8; ++mi)
#pragma unroll
        for (int ni = 0; ni < 4; ++ni) {
            const int gm = m0 + wm + mi * 16 + cr;
            const int gn = n0 + wn + ni * 16 + r15;
#pragma unroll
            for (int r = 0; r < 4; ++r)
                C[(size_t)(gm + r) * ldc + gn] =
                    f32_to_bf16(__expf(alpha * acc[mi][ni][r]));
        }
}

// ---------------------------------------------------------------------------
// Fused O-GEMM + LDS row-sum + normalize: out = (Sexp . V) / rowsum(Sexp).
// The block stages every Sexp row-panel through LDS over the full K=4096
// anyway; the XOR swizzle only permutes chunks WITHIN a row, and row sums
// are order-free -> accumulate rsum from the staged A-tile (+2 us8 LDS
// reads + ~48 VALU per thread/tile, zero extra global traffic / MFMA /
// launches). Quad shfl-combine -> lsum_lds[128] -> epilogue divide.
// BM=128 x BN=192 -> 256 blocks exact fill. Ring-3 LDS, counted
// vmcnt(10/5/0). Row-sharing XCD swizzle (FETCH 57 MB measured in R8).
// ---------------------------------------------------------------------------
__global__ __launch_bounds__(512) void gemm_out(
    const unsigned short* __restrict__ P, const unsigned short* __restrict__ Vt,
    float* __restrict__ out)
{
    const int f = blockIdx.x;           // 0..255
    const int xcd = f & 7;
    const int local = f >> 3;           // 0..31
    const int nb = local & 3;           // n-block (same XCD for all 4)
    const int rg = xcd * 8 + (local >> 2);   // row group 0..63
    const int batch = rg >> 5;
    const int mb = rg & 31;             // m-block 0..31
    const unsigned short* A = P + (size_t)batch * 16777216;
    const unsigned short* B = Vt + (size_t)batch * 4096;
    float* C = out + (size_t)batch * 3145728;
    const int m0 = mb * 128, n0 = nb * 192;
    const int lda = 4096, ldb = 8192;
    constexpr int NT = 64;

    __shared__ unsigned short As[3][128 * 64];
    __shared__ unsigned short Bs[3][192 * 64];
    __shared__ float lsum_lds[128];

    const int t = threadIdx.x;          // 0..511
    const int lane = t & 63;
    const int w = t >> 6;               // 0..7
    const int wm = (w >> 2) * 64;       // 0 / 64
    const int wn = (w & 3) * 48;        // 0..144
    const int r15 = lane & 15;
    const int qa = lane >> 4;           // 0..3

    const unsigned short* srcA[2];
    int dstA[2];
#pragma unroll
    for (int i = 0; i < 2; ++i) {
        const int c = i * 512 + t;
        const int row = c >> 3;
        const int cc = (c & 7) ^ (row & 7);
        srcA[i] = A + (size_t)(m0 + row) * lda + cc * 8;
        dstA[i] = c * 8;
    }
    const unsigned short* srcB[3];
    int dstB[3];
#pragma unroll
    for (int i = 0; i < 3; ++i) {
        const int c = i * 512 + t;
        const int row = c >> 3;
        const int cc = (c & 7) ^ (row & 7);
        srcB[i] = B + (size_t)(n0 + row) * ldb + cc * 8;
        dstB[i] = c * 8;
    }

    auto stage = [&](int buf, int kbase) {
#pragma unroll
        for (int i = 0; i < 2; ++i)
            load16(srcA[i] + kbase, &As[buf][dstA[i]]);
#pragma unroll
        for (int i = 0; i < 3; ++i)
            load16(srcB[i] + kbase, &Bs[buf][dstB[i]]);
    };

    int offA[4][2], offB[3][2];
#pragma unroll
    for (int mi = 0; mi < 4; ++mi) {
        const int row = wm + mi * 16 + r15;
#pragma unroll
        for (int ks = 0; ks < 2; ++ks)
            offA[mi][ks] = row * 64 + (((ks << 2) + qa) ^ (row & 7)) * 8;
    }
#pragma unroll
    for (int ni = 0; ni < 3; ++ni) {
        const int row = wn + ni * 16 + r15;
#pragma unroll
        for (int ks = 0; ks < 2; ++ks)
            offB[ni][ks] = row * 64 + (((ks << 2) + qa) ^ (row & 7)) * 8;
    }

    f32x4 acc[4][3];
#pragma unroll
    for (int i = 0; i < 4; ++i)
#pragma unroll
        for (int j = 0; j < 3; ++j) acc[i][j] = (f32x4){0.f, 0.f, 0.f, 0.f};
    float rsum = 0.f;                   // partial row-sum: row t>>2, quarter t&3

    stage(0, 0);
    stage(1, 64);
    stage(2, 128);

    int b = 0;
    for (int tt = 0; tt < NT; ++tt) {
        if (tt < NT - 2) {
            asm volatile("s_waitcnt vmcnt(10)" ::: "memory");
        } else if (tt == NT - 2) {
            asm volatile("s_waitcnt vmcnt(5)" ::: "memory");
        } else {
            asm volatile("s_waitcnt vmcnt(0)" ::: "memory");
        }
        __builtin_amdgcn_s_barrier();

#pragma unroll
        for (int ks = 0; ks < 2; ++ks) {
            bf16x8 aA[4], bB[3];
#pragma unroll
            for (int i = 0; i < 4; ++i)
                aA[i] = *(const bf16x8*)&As[b][offA[i][ks]];
#pragma unroll
            for (int ni = 0; ni < 3; ++ni)
                bB[ni] = *(const bf16x8*)&Bs[b][offB[ni][ks]];
#pragma unroll
            for (int i = 0; i < 4; ++i)
#pragma unroll
                for (int ni = 0; ni < 3; ++ni)
                    acc[i][ni] = __builtin_amdgcn_mfma_f32_16x16x32_bf16(
                        aA[i], bB[ni], acc[i][ni], 0, 0, 0);
        }

        // fused row-sum of the staged A-tile: all 64 k-values of row r live
        // in As[b][r*64..+64) (swizzle permutes within the row; order-free).
        {
            const us8* rp = (const us8*)&As[b][(t >> 2) * 64 + (t & 3) * 16];
            us8 v0 = rp[0], v1 = rp[1];
#pragma unroll
            for (int j = 0; j < 8; ++j)
                rsum += bf16_to_f32(v0[j]) + bf16_to_f32(v1[j]);
        }

        asm volatile("" ::: "memory");
        __builtin_amdgcn_s_barrier();

        if (tt + 3 < NT) stage(b, (tt + 3) << 6);
        b = (b == 2) ? 0 : b + 1;
    }

    // combine the 4 per-quad partials of each row, publish to LDS
    rsum += __shfl_xor(rsum, 1, 64);
    rsum += __shfl_xor(rsum, 2, 64);
    if ((t & 3) == 0) lsum_lds[t >> 2] = rsum;
    __syncthreads();

    // epilogue: divide by denominator, write fp32 out
    const int cr = (lane >> 4) * 4;
#pragma unroll
    for (int mi = 0; mi < 4; ++mi) {
        const int lr = wm + mi * 16 + cr;
        const int gm = m0 + lr;
        const float i0 = 1.f / lsum_lds[lr + 0];
        const float i1 = 1.f / lsum_lds[lr + 1];
        const float i2 = 1.f / lsum_lds[lr + 2];
        const float i3 = 1.f / lsum_lds[lr + 3];
#pragma unroll
        for (int ni = 0; ni < 3; ++ni) {
            const int gn = n0 + wn + ni * 16 + r15;
            C[(size_t)(gm + 0) * 768 + gn] = acc[mi][ni][0] * i0;
            C[(size_t)(gm + 1) * 768 + gn] = acc[mi][ni][1] * i1;
            C[(size_t)(gm + 2) * 768 + gn] = acc[mi][ni][2] * i2;
            C[(size_t)(gm + 3) * 768 + gn] = acc[mi][ni][3] * i3;
        }
    }
}

// ---------------------------------------------------------------------------
extern "C" void kernel_launch(void* const* d_in, const int* in_sizes, int n_in,
                              void* d_out, int out_size, void* d_ws, size_t ws_size,
                              hipStream_t stream) {
    const float* x  = (const float*)d_in[0];   // [2,4096,768]
    const float* Wq = (const float*)d_in[1];   // [768,768]
    const float* Wk = (const float*)d_in[2];
    const float* Wv = (const float*)d_in[3];
    float* out = (float*)d_out;                // [2,4096,768] fp32

    char* base = (char*)d_ws;
    size_t off = 0;
    auto alloc = [&](size_t b) { char* p = base + off; off += (b + 255) & ~(size_t)255; return p; };

    unsigned short* Xbf = (unsigned short*)alloc(8192ull * 768 * 2);   // x as bf16
    unsigned short* WqT = (unsigned short*)alloc(768ull * 768 * 2);    // W^T bf16, x3 contiguous
    unsigned short* WkT = (unsigned short*)alloc(768ull * 768 * 2);
    unsigned short* WvT = (unsigned short*)alloc(768ull * 768 * 2);
    unsigned short* Qb  = (unsigned short*)alloc(8192ull * 768 * 2);   // Q bf16
    unsigned short* Kb  = (unsigned short*)alloc(8192ull * 768 * 2);   // K bf16
    unsigned short* Vt  = (unsigned short*)alloc(768ull * 8192 * 2);   // V^T bf16 [768,8192]
    unsigned short* Sexp = (unsigned short*)alloc(2ull * 4096 * 4096 * 2); // exp(scores) bf16
    (void)ws_size; (void)in_sizes; (void)n_in; (void)out_size; (void)WkT; (void)WvT;

    // 1) x -> bf16, W -> W^T bf16
    prep<<<dim3(3264), dim3(1024), 0, stream>>>(x, Xbf, Wq, Wk, Wv, WqT, WkT, WvT);
    // 2) Q, K and V^T in ONE launch (512 blocks, 2 exact rounds)
    qkv3<<<dim3(512), dim3(512), 0, stream>>>(Xbf, WqT, Qb, Kb, Vt);
    // 3) Sexp = exp(Q.K^T / sqrt(768)) bf16, store-only epilogue
    gemm_s_exp2<<<dim3(512), dim3(512), 0, stream>>>(
        Qb, Kb, Sexp, 0.03608439182435161f);
    // 4) out = (Sexp . V) / rowsum(Sexp) -- row sums fused via LDS A-tiles
    gemm_out<<<dim3(256), dim3(512), 0, stream>>>(Sexp, Vt, out);
}